// Round 6
// baseline (6469.677 us; speedup 1.0000x reference)
//
#include <hip/hip_runtime.h>
#include <hip/hip_bf16.h>

// LiquidLinear: xin = x@Wi^T + bi ; scan: h' = (1-sig(tau))h + sig(tau)tanh(xin_t + h@Wr^T + br)
// outs = hs@Wo^T + bo ; outputs = [outs (B,S,DOUT) fp32][h_final (B,H) fp32]
// B=64 S=1024 DIN=H=DOUT=512
//
// R6: K-SPLIT scan + single-round-trip tagged-data exchange.
//  - 8 blocks = 4 groups x 2 k-slices. Block sl owns h cols [sl*256,+256) and holds
//    Wr[all 512 n][own 256 k] register-stationary (128 VGPR/wave weights).
//  - Each step: MFMA partial I over own k for ALL n (before exchange!), publish
//    peer-half partials as u64 (tag<<32 | fp32) fire-and-forget atomic swaps into
//    parity-2 slots; own-half partials go to LDS. Consumer RMW-polls directly on its
//    8 tagged words (detection == fetch, ONE round trip), then add + tanh only.
//  - No flags, no vm drains, no release/acquire (R4's wbl2/inv storms), placement-
//    independent (all sync via IF-serialized atomics; R5-proven primitives).
//  - Overwrite safety (parity-2 + block barriers): A publishes tag t+1 into slot t&1
//    ==> A passed sync2(t-1) ==> A consumed B's tag t ==> B passed sync2(t-2) ==> B
//    consumed A's tag t-1 (the value overwritten). Same chain: poller of t+1 can
//    never see t+3, so tag>=t+1 implies ==t+1.

typedef short bf16x8 __attribute__((ext_vector_type(8)));
typedef float f32x4 __attribute__((ext_vector_type(4)));
typedef float floatv4 __attribute__((ext_vector_type(4)));
typedef unsigned short ushort4v __attribute__((ext_vector_type(4)));

#define NSTEP 1024

__device__ __forceinline__ unsigned short f2bf(float f) {
    union { float f; unsigned u; } v; v.f = f;
    unsigned r = v.u + 0x7FFF + ((v.u >> 16) & 1);   // RNE
    return (unsigned short)(r >> 16);
}
__device__ __forceinline__ float bf2f(unsigned short u) {
    union { unsigned u; float f; } v; v.u = ((unsigned)u) << 16;
    return v.f;
}

// ---------------------------------------------------------------- init exchange buffer
__global__ void init_pbuf(unsigned long long* p) {
    int i = blockIdx.x * blockDim.x + threadIdx.x;
    #pragma unroll
    for (int e = 0; e < 4; e++) p[(size_t)i * 4 + e] = 0ULL;   // tag 0 < first expected tag 1
}

// ---------------------------------------------------------------- GEMM1: xin = x @ Wi^T + bi
__global__ __launch_bounds__(256) void gemm_xin(
    const float* __restrict__ X, const float* __restrict__ Wi,
    const float* __restrict__ bi, float* __restrict__ xin)
{
    __shared__ unsigned short As[128][40];
    __shared__ unsigned short Bs[128][40];
    const int bm = blockIdx.x, bn = blockIdx.y;
    const int tid = threadIdx.x, w = tid >> 6, l = tid & 63;
    const int wm = w >> 1, wn = w & 1;
    f32x4 acc[4][4] = {};

    for (int kt = 0; kt < 512; kt += 32) {
        __syncthreads();
        #pragma unroll
        for (int j = 0; j < 4; j++) {
            int q = tid + 256 * j;
            int row = q >> 3, c4 = (q & 7) * 4;
            floatv4 va = *(const floatv4*)&X[(size_t)(bm * 128 + row) * 512 + kt + c4];
            floatv4 vb = *(const floatv4*)&Wi[(size_t)(bn * 128 + row) * 512 + kt + c4];
            ushort4v pa, pb;
            #pragma unroll
            for (int e = 0; e < 4; e++) { pa[e] = f2bf(va[e]); pb[e] = f2bf(vb[e]); }
            *(ushort4v*)&As[row][c4] = pa;
            *(ushort4v*)&Bs[row][c4] = pb;
        }
        __syncthreads();
        bf16x8 a[4], b[4];
        #pragma unroll
        for (int i = 0; i < 4; i++)
            a[i] = *(const bf16x8*)&As[wm * 64 + i * 16 + (l & 15)][(l >> 4) * 8];
        #pragma unroll
        for (int i = 0; i < 4; i++)
            b[i] = *(const bf16x8*)&Bs[wn * 64 + i * 16 + (l & 15)][(l >> 4) * 8];
        #pragma unroll
        for (int i = 0; i < 4; i++)
            #pragma unroll
            for (int j = 0; j < 4; j++)
                acc[i][j] = __builtin_amdgcn_mfma_f32_16x16x32_bf16(a[i], b[j], acc[i][j], 0, 0, 0);
    }
    #pragma unroll
    for (int i = 0; i < 4; i++)
        #pragma unroll
        for (int j = 0; j < 4; j++)
            #pragma unroll
            for (int r = 0; r < 4; r++) {
                int m = bm * 128 + wm * 64 + i * 16 + (l >> 4) * 4 + r;
                int n = bn * 128 + wn * 64 + j * 16 + (l & 15);
                int bb = m >> 10, tt = m & 1023;
                xin[((size_t)tt * 64 + bb) * 512 + n] = acc[i][j][r] + bi[n];
            }
}

// ---------------------------------------------------------------- GEMM3: outs = hs @ Wo^T + bo
__global__ __launch_bounds__(256) void gemm_out(
    const unsigned short* __restrict__ hs, const float* __restrict__ Wo,
    const float* __restrict__ bo, float* __restrict__ out)
{
    __shared__ unsigned short As[128][40];
    __shared__ unsigned short Bs[128][40];
    const int bm = blockIdx.x, bn = blockIdx.y;
    const int tid = threadIdx.x, w = tid >> 6, l = tid & 63;
    const int wm = w >> 1, wn = w & 1;
    f32x4 acc[4][4] = {};

    for (int kt = 0; kt < 512; kt += 32) {
        __syncthreads();
        #pragma unroll
        for (int j = 0; j < 2; j++) {
            int q = tid + 256 * j;
            int row = q >> 2, c8 = (q & 3) * 8;
            int r = bm * 128 + row;
            int ra = (r & 1023) * 64 + (r >> 10);
            bf16x8 v = *(const bf16x8*)&hs[(size_t)ra * 512 + kt + c8];
            *(bf16x8*)&As[row][c8] = v;
        }
        #pragma unroll
        for (int j = 0; j < 4; j++) {
            int q = tid + 256 * j;
            int row = q >> 3, c4 = (q & 7) * 4;
            floatv4 vb = *(const floatv4*)&Wo[(size_t)(bn * 128 + row) * 512 + kt + c4];
            ushort4v pb;
            #pragma unroll
            for (int e = 0; e < 4; e++) pb[e] = f2bf(vb[e]);
            *(ushort4v*)&Bs[row][c4] = pb;
        }
        __syncthreads();
        bf16x8 a[4], b[4];
        #pragma unroll
        for (int i = 0; i < 4; i++)
            a[i] = *(const bf16x8*)&As[wm * 64 + i * 16 + (l & 15)][(l >> 4) * 8];
        #pragma unroll
        for (int i = 0; i < 4; i++)
            b[i] = *(const bf16x8*)&Bs[wn * 64 + i * 16 + (l & 15)][(l >> 4) * 8];
        #pragma unroll
        for (int i = 0; i < 4; i++)
            #pragma unroll
            for (int j = 0; j < 4; j++)
                acc[i][j] = __builtin_amdgcn_mfma_f32_16x16x32_bf16(a[i], b[j], acc[i][j], 0, 0, 0);
    }
    #pragma unroll
    for (int i = 0; i < 4; i++)
        #pragma unroll
        for (int j = 0; j < 4; j++)
            #pragma unroll
            for (int r = 0; r < 4; r++) {
                int m = bm * 128 + wm * 64 + i * 16 + (l >> 4) * 4 + r;
                int n = bn * 128 + wn * 64 + j * 16 + (l & 15);
                out[(size_t)m * 512 + n] = acc[i][j][r] + bo[n];
            }
}

// ---------------------------------------------------------------- scan (K-split)
// 8 blocks: group g = bid&3 (16 batches), k-slice sl = bid>>2.
// pbuf: u64 [4 group][2 destBlock][2 par][256 nlocal][16 row]; word = (tag<<32)|fp32.
__global__ __launch_bounds__(512, 2) void scan_k(
    const float* __restrict__ Wr, const float* __restrict__ brv,
    const float* __restrict__ tau, const float* __restrict__ xin,
    unsigned short* __restrict__ hs, unsigned long long* __restrict__ pbuf,
    float* __restrict__ hfinal)
{
    const int g  = blockIdx.x & 3;
    const int sl = blockIdx.x >> 2;      // 0..1 : owns h cols / k range [sl*256, +256)
    const int tid = threadIdx.x, w = tid >> 6, l = tid & 63;

    __shared__ unsigned short hHi[16][264];   // own-half h, bf16 hi (local k)
    __shared__ unsigned short hLo[16][264];   // bf16 lo residual
    __shared__ float pLoc[16][260];           // own-k partials for own n-half

    for (int i = tid; i < 16 * 264; i += 512) { (&hHi[0][0])[i] = 0; (&hLo[0][0])[i] = 0; }

    // ---- register-stationary weights: wave w holds Wr[n = w*64..+64)[k = own 256]
    // 4 n-tiles x 8 k-frags = 32 bf16x8 = 128 VGPR
    bf16x8 wf[4][8];
    #pragma unroll
    for (int tile = 0; tile < 4; tile++)
        #pragma unroll
        for (int kt = 0; kt < 8; kt++) {
            const float* p = &Wr[(size_t)(w * 64 + tile * 16 + (l & 15)) * 512
                                 + sl * 256 + kt * 32 + (l >> 4) * 8];
            bf16x8 f;
            #pragma unroll
            for (int e = 0; e < 8; e++) f[e] = (short)f2bf(p[e]);
            wf[tile][kt] = f;
        }

    // ---- update-phase ownership: thread owns cols j0,j1 (global), rows mr4..mr4+3
    const int j0l = w * 32 + (l & 15), j1l = j0l + 16;
    const int j0 = sl * 256 + j0l,     j1 = sl * 256 + j1l;
    const float d0 = 1.f / (1.f + __expf(-tau[j0])), d0c = 1.f - d0, br0 = brv[j0];
    const float d1 = 1.f / (1.f + __expf(-tau[j1])), d1c = 1.f - d1, br1 = brv[j1];
    float hold0[4] = {}, hold1[4] = {};
    const int mr4 = (l >> 4) * 4;

    // ---- publish/consume bases
    const bool isPub = ((w >> 2) != sl);            // wave's n-half belongs to peer
    const int  nl0   = (w & 3) * 64 + (l & 15);     // local n within the half (+tile*16)
    unsigned long long* pubBase = pbuf + (size_t)(g * 2 + (1 - sl)) * 2 * 4096;
    unsigned long long* conBase = pbuf + (size_t)(g * 2 + sl) * 2 * 4096;

    __syncthreads();

    // prologue xin (t=0)
    float xv0[4], xv1[4], xn0[4], xn1[4];
    #pragma unroll
    for (int r = 0; r < 4; r++) {
        xv0[r] = xin[((size_t)0 * 64 + g * 16 + mr4 + r) * 512 + j0];
        xv1[r] = xin[((size_t)0 * 64 + g * 16 + mr4 + r) * 512 + j1];
    }

    for (int t = 0; t < NSTEP; ++t) {
        // prefetch next xin (older than the publish swaps -> no extra waits)
        if (t + 1 < NSTEP) {
            #pragma unroll
            for (int r = 0; r < 4; r++) {
                xn0[r] = xin[((size_t)(t + 1) * 64 + g * 16 + mr4 + r) * 512 + j0];
                xn1[r] = xin[((size_t)(t + 1) * 64 + g * 16 + mr4 + r) * 512 + j1];
            }
        }
        // partial I over OWN k for this wave's 64 n-cols (hi+lo into same acc)
        f32x4 acc[4] = {};
        #pragma unroll
        for (int kt = 0; kt < 8; kt++) {
            bf16x8 ah = *(const bf16x8*)&hHi[l & 15][kt * 32 + (l >> 4) * 8];
            bf16x8 al = *(const bf16x8*)&hLo[l & 15][kt * 32 + (l >> 4) * 8];
            #pragma unroll
            for (int tile = 0; tile < 4; tile++) {
                acc[tile] = __builtin_amdgcn_mfma_f32_16x16x32_bf16(ah, wf[tile][kt], acc[tile], 0, 0, 0);
                acc[tile] = __builtin_amdgcn_mfma_f32_16x16x32_bf16(al, wf[tile][kt], acc[tile], 0, 0, 0);
            }
        }
        const int par = t & 1;
        const unsigned tag = (unsigned)(t + 1);

        if (isPub) {
            // fire-and-forget tagged swaps to peer (16 u64)
            unsigned long long* pb = pubBase + (size_t)par * 4096;
            #pragma unroll
            for (int tile = 0; tile < 4; tile++)
                #pragma unroll
                for (int r = 0; r < 4; r++) {
                    int addr = (nl0 + tile * 16) * 16 + mr4 + r;
                    unsigned long long v = ((unsigned long long)tag << 32)
                                         | (unsigned long long)__float_as_uint(acc[tile][r]);
                    (void)__hip_atomic_exchange(&pb[addr], v, __ATOMIC_RELAXED, __HIP_MEMORY_SCOPE_AGENT);
                }
        } else {
            #pragma unroll
            for (int tile = 0; tile < 4; tile++)
                #pragma unroll
                for (int r = 0; r < 4; r++)
                    pLoc[mr4 + r][nl0 + tile * 16] = acc[tile][r];
        }
        __syncthreads();                  // pLoc ready; hHi/hLo free for rewrite

        // ONE-round-trip consume: poll own 8 tagged words
        unsigned long long q[8];
        {
            unsigned long long* cb = conBase + (size_t)par * 4096;
            const int a0 = j0l * 16 + mr4, a1 = j1l * 16 + mr4;
            while (true) {
                #pragma unroll
                for (int e = 0; e < 4; e++) {
                    q[e]     = __hip_atomic_fetch_add(&cb[a0 + e], 0ULL, __ATOMIC_RELAXED, __HIP_MEMORY_SCOPE_AGENT);
                    q[4 + e] = __hip_atomic_fetch_add(&cb[a1 + e], 0ULL, __ATOMIC_RELAXED, __HIP_MEMORY_SCOPE_AGENT);
                }
                unsigned mn = 0xffffffffu;
                #pragma unroll
                for (int e = 0; e < 8; e++) {
                    unsigned tg = (unsigned)(q[e] >> 32);
                    mn = (tg < mn) ? tg : mn;
                }
                if (mn >= tag) break;
                __builtin_amdgcn_s_sleep(1);
            }
        }
        // update: I = ownP + peerP + xin + br ; h' = (1-d)h + d*tanh(I)
        #pragma unroll
        for (int r = 0; r < 4; r++) {
            float I0 = pLoc[mr4 + r][j0l] + __uint_as_float((unsigned)q[r])     + xv0[r] + br0;
            float I1 = pLoc[mr4 + r][j1l] + __uint_as_float((unsigned)q[4 + r]) + xv1[r] + br1;
            float h0 = d0c * hold0[r] + d0 * tanhf(I0); hold0[r] = h0;
            float h1 = d1c * hold1[r] + d1 * tanhf(I1); hold1[r] = h1;
            unsigned short hh0 = f2bf(h0), hh1 = f2bf(h1);
            hHi[mr4 + r][j0l] = hh0; hLo[mr4 + r][j0l] = f2bf(h0 - bf2f(hh0));
            hHi[mr4 + r][j1l] = hh1; hLo[mr4 + r][j1l] = f2bf(h1 - bf2f(hh1));
            size_t row = (size_t)t * 64 + g * 16 + mr4 + r;
            hs[row * 512 + j0] = hh0;
            hs[row * 512 + j1] = hh1;
        }
        #pragma unroll
        for (int r = 0; r < 4; r++) { xv0[r] = xn0[r]; xv1[r] = xn1[r]; }
        __syncthreads();                  // h_t in LDS for next MFMA
    }

    #pragma unroll
    for (int r = 0; r < 4; r++) {
        hfinal[(size_t)(g * 16 + mr4 + r) * 512 + j0] = hold0[r];
        hfinal[(size_t)(g * 16 + mr4 + r) * 512 + j1] = hold1[r];
    }
}

// ---------------------------------------------------------------- launch
extern "C" void kernel_launch(void* const* d_in, const int* in_sizes, int n_in,
                              void* d_out, int out_size, void* d_ws, size_t ws_size,
                              hipStream_t stream) {
    const float* x   = (const float*)d_in[0];
    const float* Wi  = (const float*)d_in[1];
    const float* bi  = (const float*)d_in[2];
    const float* Wr  = (const float*)d_in[3];
    const float* br  = (const float*)d_in[4];
    const float* tau = (const float*)d_in[5];
    const float* Wo  = (const float*)d_in[6];
    const float* bo  = (const float*)d_in[7];

    float* out    = (float*)d_out;
    float* xin    = (float*)d_out;                       // reuse outs region for xin [S,B,H] fp32
    float* hfinal = (float*)d_out + (size_t)33554432;    // after B*S*DOUT

    // ws: hs bf16 [S,B,H] (64 MiB) | pbuf u64 [4][2][2][256][16] (512 KiB)
    unsigned short* hs        = (unsigned short*)d_ws;
    unsigned long long* pbuf  = (unsigned long long*)((char*)d_ws + (size_t)67108864);

    hipLaunchKernelGGL(init_pbuf, dim3(64), dim3(256), 0, stream, pbuf);
    hipLaunchKernelGGL(gemm_xin, dim3(512, 4), dim3(256), 0, stream, x, Wi, bi, xin);
    hipLaunchKernelGGL(scan_k, dim3(8), dim3(512), 0, stream,
                       Wr, br, tau, xin, hs, pbuf, hfinal);
    hipLaunchKernelGGL(gemm_out, dim3(512, 4), dim3(256), 0, stream, hs, Wo, bo, out);
}

// Round 9
// 5498.905 us; speedup vs baseline: 1.1765x; 1.1765x over previous
//
#include <hip/hip_runtime.h>
#include <hip/hip_bf16.h>
#include <hip/hip_fp16.h>

// LiquidLinear: xin = x@Wi^T + bi ; scan: h' = (1-sig(tau))h + sig(tau)tanh(xin_t + h@Wr^T + br)
// outs = hs@Wo^T + bo ; outputs = [outs (B,S,DOUT) fp32][h_final (B,H) fp32]
// B=64 S=1024 DIN=H=DOUT=512
//
// R9: EXCHANGE-FREE scan. One block per 16-batch group (4 blocks total); each block
// owns the ENTIRE recurrence for its batches: full Wr fp16 resident in
// VGPR (46 frags/wave = 184 regs) + LDS (18 chunks/wave = 144KB). h broadcast via a
// 16KB XOR-swizzled LDS fp16 buffer. No inter-block sync of any kind (R2/R7/R8
// timeouts were all cross-block protocol bugs; R5's working protocol cost 4us/step
// at IF). fp16 single-pass MFMA replaces bf16 hi/lo dual-pass: more accurate
// (fp16 Wr: 2e-5 abs vs bf16 1.7e-4) at HALF the MFMA count. GEMMs fp16 too.

typedef _Float16 f16x8 __attribute__((ext_vector_type(8)));
typedef float f32x4 __attribute__((ext_vector_type(4)));
typedef float floatv4 __attribute__((ext_vector_type(4)));
typedef unsigned short ushort4v __attribute__((ext_vector_type(4)));
typedef unsigned int uint4v __attribute__((ext_vector_type(4)));

#define NSTEP 1024

__device__ __forceinline__ unsigned short f2h(float f) {
    _Float16 h = (_Float16)f;
    return *(unsigned short*)&h;
}
__device__ __forceinline__ float tanh_fast(float x) {
    // 1 - 2/(e^{2x}+1): monotone, saturates to +-1 without NaN at extremes
    float e = __expf(2.f * x);
    return 1.f - 2.f / (e + 1.f);
}

// ---------------------------------------------------------------- GEMM1: xin = x @ Wi^T + bi
__global__ __launch_bounds__(256) void gemm_xin(
    const float* __restrict__ X, const float* __restrict__ Wi,
    const float* __restrict__ bi, float* __restrict__ xin)
{
    __shared__ unsigned short As[128][40];
    __shared__ unsigned short Bs[128][40];
    const int bm = blockIdx.x, bn = blockIdx.y;
    const int tid = threadIdx.x, w = tid >> 6, l = tid & 63;
    const int wm = w >> 1, wn = w & 1;
    f32x4 acc[4][4] = {};

    for (int kt = 0; kt < 512; kt += 32) {
        __syncthreads();
        #pragma unroll
        for (int j = 0; j < 4; j++) {
            int q = tid + 256 * j;
            int row = q >> 3, c4 = (q & 7) * 4;
            floatv4 va = *(const floatv4*)&X[(size_t)(bm * 128 + row) * 512 + kt + c4];
            floatv4 vb = *(const floatv4*)&Wi[(size_t)(bn * 128 + row) * 512 + kt + c4];
            ushort4v pa, pb;
            #pragma unroll
            for (int e = 0; e < 4; e++) { pa[e] = f2h(va[e]); pb[e] = f2h(vb[e]); }
            *(ushort4v*)&As[row][c4] = pa;
            *(ushort4v*)&Bs[row][c4] = pb;
        }
        __syncthreads();
        f16x8 a[4], b[4];
        #pragma unroll
        for (int i = 0; i < 4; i++)
            a[i] = *(const f16x8*)&As[wm * 64 + i * 16 + (l & 15)][(l >> 4) * 8];
        #pragma unroll
        for (int i = 0; i < 4; i++)
            b[i] = *(const f16x8*)&Bs[wn * 64 + i * 16 + (l & 15)][(l >> 4) * 8];
        #pragma unroll
        for (int i = 0; i < 4; i++)
            #pragma unroll
            for (int j = 0; j < 4; j++)
                acc[i][j] = __builtin_amdgcn_mfma_f32_16x16x32_f16(a[i], b[j], acc[i][j], 0, 0, 0);
    }
    #pragma unroll
    for (int i = 0; i < 4; i++)
        #pragma unroll
        for (int j = 0; j < 4; j++)
            #pragma unroll
            for (int r = 0; r < 4; r++) {
                int m = bm * 128 + wm * 64 + i * 16 + (l >> 4) * 4 + r;
                int n = bn * 128 + wn * 64 + j * 16 + (l & 15);
                int bb = m >> 10, tt = m & 1023;
                xin[((size_t)tt * 64 + bb) * 512 + n] = acc[i][j][r] + bi[n];
            }
}

// ---------------------------------------------------------------- GEMM3: outs = hs @ Wo^T + bo
__global__ __launch_bounds__(256) void gemm_out(
    const unsigned short* __restrict__ hs, const float* __restrict__ Wo,
    const float* __restrict__ bo, float* __restrict__ out)
{
    __shared__ unsigned short As[128][40];
    __shared__ unsigned short Bs[128][40];
    const int bm = blockIdx.x, bn = blockIdx.y;
    const int tid = threadIdx.x, w = tid >> 6, l = tid & 63;
    const int wm = w >> 1, wn = w & 1;
    f32x4 acc[4][4] = {};

    for (int kt = 0; kt < 512; kt += 32) {
        __syncthreads();
        #pragma unroll
        for (int j = 0; j < 2; j++) {
            int q = tid + 256 * j;
            int row = q >> 2, c8 = (q & 3) * 8;
            int r = bm * 128 + row;
            int ra = (r & 1023) * 64 + (r >> 10);
            f16x8 v = *(const f16x8*)&hs[(size_t)ra * 512 + kt + c8];
            *(f16x8*)&As[row][c8] = v;
        }
        #pragma unroll
        for (int j = 0; j < 4; j++) {
            int q = tid + 256 * j;
            int row = q >> 3, c4 = (q & 7) * 4;
            floatv4 vb = *(const floatv4*)&Wo[(size_t)(bn * 128 + row) * 512 + kt + c4];
            ushort4v pb;
            #pragma unroll
            for (int e = 0; e < 4; e++) pb[e] = f2h(vb[e]);
            *(ushort4v*)&Bs[row][c4] = pb;
        }
        __syncthreads();
        f16x8 a[4], b[4];
        #pragma unroll
        for (int i = 0; i < 4; i++)
            a[i] = *(const f16x8*)&As[wm * 64 + i * 16 + (l & 15)][(l >> 4) * 8];
        #pragma unroll
        for (int i = 0; i < 4; i++)
            b[i] = *(const f16x8*)&Bs[wn * 64 + i * 16 + (l & 15)][(l >> 4) * 8];
        #pragma unroll
        for (int i = 0; i < 4; i++)
            #pragma unroll
            for (int j = 0; j < 4; j++)
                acc[i][j] = __builtin_amdgcn_mfma_f32_16x16x32_f16(a[i], b[j], acc[i][j], 0, 0, 0);
    }
    #pragma unroll
    for (int i = 0; i < 4; i++)
        #pragma unroll
        for (int j = 0; j < 4; j++)
            #pragma unroll
            for (int r = 0; r < 4; r++) {
                int m = bm * 128 + wm * 64 + i * 16 + (l >> 4) * 4 + r;
                int n = bn * 128 + wn * 64 + j * 16 + (l & 15);
                out[(size_t)m * 512 + n] = acc[i][j][r] + bo[n];
            }
}

// ---------------------------------------------------------------- scan (exchange-free)
// 4 blocks; block g owns batches [g*16,+16), computes ALL 512 h-cols per step.
// Wave w owns n-cols [w*64,+64) (4 tiles of 16). Weights per wave: 64KB fp16,
// split VGPR (tiles 0,1: kt<11; tiles 2,3: kt<12 -> 46 frags = 184 regs) and
// LDS (18 chunks x 1KB). h: [16 rows][512] fp16 in LDS, XOR-swizzled
// (byte ^= (row&7)<<4) -> A-frag ds_read_b128 at the 8-cycle bank floor.
__global__ __launch_bounds__(512, 2) void scan_g(
    const float* __restrict__ Wr, const float* __restrict__ brv,
    const float* __restrict__ tau, const float* __restrict__ xin,
    unsigned short* __restrict__ hs, float* __restrict__ hfinal)
{
    const int g = blockIdx.x;
    const int tid = threadIdx.x, w = tid >> 6, l = tid & 63;

    __shared__ unsigned short wlds[73728];   // 144KB: 8 waves x 18 chunks x 512 ushort
    __shared__ unsigned short h16[8192];     // 16KB: h fp16 [16][512], XOR-swizzled

    // zero h16 (h0 = 0)
    ((uint4v*)h16)[tid] = uint4v{0, 0, 0, 0};
    ((uint4v*)h16)[tid + 512] = uint4v{0, 0, 0, 0};

    // ---- load weights: wave w, cols w*64 + tile*16 + (l&15), k = kt*32 + (l>>4)*8
    f16x8 wv0[11], wv1[11], wv2[12], wv3[12];
    #pragma unroll
    for (int kt = 0; kt < 16; kt++) {
        f16x8 f[4];
        #pragma unroll
        for (int tile = 0; tile < 4; tile++) {
            const float* p = &Wr[(size_t)(w * 64 + tile * 16 + (l & 15)) * 512 + kt * 32 + (l >> 4) * 8];
            #pragma unroll
            for (int e = 0; e < 8; e++) f[tile][e] = (_Float16)p[e];
        }
        if (kt < 11) { wv0[kt] = f[0]; wv1[kt] = f[1]; wv2[kt] = f[2]; wv3[kt] = f[3]; }
        else if (kt == 11) {
            wv2[11] = f[2]; wv3[11] = f[3];
            *(f16x8*)&wlds[(w * 18 + 0 + (kt - 11)) * 512 + l * 8] = f[0];
            *(f16x8*)&wlds[(w * 18 + 5 + (kt - 11)) * 512 + l * 8] = f[1];
        } else {
            *(f16x8*)&wlds[(w * 18 + 0  + (kt - 11)) * 512 + l * 8] = f[0];
            *(f16x8*)&wlds[(w * 18 + 5  + (kt - 11)) * 512 + l * 8] = f[1];
            *(f16x8*)&wlds[(w * 18 + 10 + (kt - 12)) * 512 + l * 8] = f[2];
            *(f16x8*)&wlds[(w * 18 + 14 + (kt - 12)) * 512 + l * 8] = f[3];
        }
    }

    // ---- per-col constants (4 tiles)
    float dd[4], dc[4], bb[4];
    #pragma unroll
    for (int tile = 0; tile < 4; tile++) {
        int col = w * 64 + tile * 16 + (l & 15);
        float s = 1.f / (1.f + __expf(-tau[col]));
        dd[tile] = s; dc[tile] = 1.f - s; bb[tile] = brv[col];
    }
    const int mr4 = (l >> 4) * 4;            // this thread's 4 batch rows
    // h state packed fp16 pairs: hpk[tile][rpair] = rows (2rp, 2rp+1)
    unsigned hpk[4][2] = {};

    __syncthreads();                          // h16 zeros + wlds ready

    for (int t = 0; t < NSTEP; ++t) {
        // xin for this step (independent loads; L3-resident; cover under MFMA)
        float xv[4][4];
        #pragma unroll
        for (int tile = 0; tile < 4; tile++)
            #pragma unroll
            for (int r = 0; r < 4; r++)
                xv[tile][r] = xin[((size_t)t * 64 + g * 16 + mr4 + r) * 512
                                  + w * 64 + tile * 16 + (l & 15)];

        // I = h @ Wr^T over all 512 k, 4 acc chains
        f32x4 acc[4] = {};
        #pragma unroll
        for (int kt = 0; kt < 11; kt++) {
            int abyte = (((l & 15) * 1024) + kt * 64 + ((l >> 4) * 16)) ^ ((l & 7) << 4);
            f16x8 ah = *(const f16x8*)((const char*)h16 + abyte);
            acc[0] = __builtin_amdgcn_mfma_f32_16x16x32_f16(ah, wv0[kt], acc[0], 0, 0, 0);
            acc[1] = __builtin_amdgcn_mfma_f32_16x16x32_f16(ah, wv1[kt], acc[1], 0, 0, 0);
            acc[2] = __builtin_amdgcn_mfma_f32_16x16x32_f16(ah, wv2[kt], acc[2], 0, 0, 0);
            acc[3] = __builtin_amdgcn_mfma_f32_16x16x32_f16(ah, wv3[kt], acc[3], 0, 0, 0);
        }
        {   // kt = 11: tiles 0,1 from LDS; tiles 2,3 from VGPR
            int abyte = (((l & 15) * 1024) + 11 * 64 + ((l >> 4) * 16)) ^ ((l & 7) << 4);
            f16x8 ah = *(const f16x8*)((const char*)h16 + abyte);
            f16x8 b0 = *(const f16x8*)&wlds[(w * 18 + 0) * 512 + l * 8];
            f16x8 b1 = *(const f16x8*)&wlds[(w * 18 + 5) * 512 + l * 8];
            acc[0] = __builtin_amdgcn_mfma_f32_16x16x32_f16(ah, b0, acc[0], 0, 0, 0);
            acc[1] = __builtin_amdgcn_mfma_f32_16x16x32_f16(ah, b1, acc[1], 0, 0, 0);
            acc[2] = __builtin_amdgcn_mfma_f32_16x16x32_f16(ah, wv2[11], acc[2], 0, 0, 0);
            acc[3] = __builtin_amdgcn_mfma_f32_16x16x32_f16(ah, wv3[11], acc[3], 0, 0, 0);
        }
        #pragma unroll
        for (int kt = 12; kt < 16; kt++) {
            int abyte = (((l & 15) * 1024) + kt * 64 + ((l >> 4) * 16)) ^ ((l & 7) << 4);
            f16x8 ah = *(const f16x8*)((const char*)h16 + abyte);
            f16x8 b0 = *(const f16x8*)&wlds[(w * 18 + 0  + (kt - 11)) * 512 + l * 8];
            f16x8 b1 = *(const f16x8*)&wlds[(w * 18 + 5  + (kt - 11)) * 512 + l * 8];
            f16x8 b2 = *(const f16x8*)&wlds[(w * 18 + 10 + (kt - 12)) * 512 + l * 8];
            f16x8 b3 = *(const f16x8*)&wlds[(w * 18 + 14 + (kt - 12)) * 512 + l * 8];
            acc[0] = __builtin_amdgcn_mfma_f32_16x16x32_f16(ah, b0, acc[0], 0, 0, 0);
            acc[1] = __builtin_amdgcn_mfma_f32_16x16x32_f16(ah, b1, acc[1], 0, 0, 0);
            acc[2] = __builtin_amdgcn_mfma_f32_16x16x32_f16(ah, b2, acc[2], 0, 0, 0);
            acc[3] = __builtin_amdgcn_mfma_f32_16x16x32_f16(ah, b3, acc[3], 0, 0, 0);
        }
        __syncthreads();                      // all reads of h_t complete

        // update h for this thread's 16 elems (4 tiles x 4 rows)
        #pragma unroll
        for (int tile = 0; tile < 4; tile++) {
            unsigned np[2];
            #pragma unroll
            for (int rp = 0; rp < 2; rp++) {
                unsigned pk = hpk[tile][rp];
                unsigned nv = 0;
                #pragma unroll
                for (int hbit = 0; hbit < 2; hbit++) {
                    int r = rp * 2 + hbit;
                    _Float16 holdh;
                    *(unsigned short*)&holdh = (unsigned short)((pk >> (hbit * 16)) & 0xffff);
                    float I = acc[tile][r] + xv[tile][r] + bb[tile];
                    float hn = dc[tile] * (float)holdh + dd[tile] * tanh_fast(I);
                    unsigned short hq = f2h(hn);
                    nv |= ((unsigned)hq) << (hbit * 16);
                    int row = mr4 + r, col = w * 64 + tile * 16 + (l & 15);
                    int byte = (row * 1024 + col * 2) ^ ((row & 7) << 4);
                    *(unsigned short*)((char*)h16 + byte) = hq;
                    hs[((size_t)t * 64 + g * 16 + row) * 512 + col] = hq;
                }
                np[rp] = nv;
            }
            hpk[tile][0] = np[0]; hpk[tile][1] = np[1];
        }
        __syncthreads();                      // h_{t+1} visible to all waves
    }

    // h_final fp32 (from packed fp16 state)
    #pragma unroll
    for (int tile = 0; tile < 4; tile++)
        #pragma unroll
        for (int r = 0; r < 4; r++) {
            _Float16 hv;
            *(unsigned short*)&hv = (unsigned short)((hpk[tile][r >> 1] >> ((r & 1) * 16)) & 0xffff);
            int col = w * 64 + tile * 16 + (l & 15);
            hfinal[(size_t)(g * 16 + mr4 + r) * 512 + col] = (float)hv;
        }
}

// ---------------------------------------------------------------- launch
extern "C" void kernel_launch(void* const* d_in, const int* in_sizes, int n_in,
                              void* d_out, int out_size, void* d_ws, size_t ws_size,
                              hipStream_t stream) {
    const float* x   = (const float*)d_in[0];
    const float* Wi  = (const float*)d_in[1];
    const float* bi  = (const float*)d_in[2];
    const float* Wr  = (const float*)d_in[3];
    const float* br  = (const float*)d_in[4];
    const float* tau = (const float*)d_in[5];
    const float* Wo  = (const float*)d_in[6];
    const float* bo  = (const float*)d_in[7];

    float* out    = (float*)d_out;
    float* xin    = (float*)d_out;                       // reuse outs region for xin [S,B,H] fp32
    float* hfinal = (float*)d_out + (size_t)33554432;    // after B*S*DOUT

    // ws: hs fp16 [S,B,H] (64 MiB). Nothing else.
    unsigned short* hs = (unsigned short*)d_ws;

    hipLaunchKernelGGL(gemm_xin, dim3(512, 4), dim3(256), 0, stream, x, Wi, bi, xin);
    hipLaunchKernelGGL(scan_g, dim3(4), dim3(512), 0, stream, Wr, br, tau, xin, hs, hfinal);
    hipLaunchKernelGGL(gemm_out, dim3(512, 4), dim3(256), 0, stream, hs, Wo, bo, out);
}

// Round 10
// 5496.917 us; speedup vs baseline: 1.1770x; 1.0004x over previous
//
#include <hip/hip_runtime.h>
#include <hip/hip_bf16.h>
#include <hip/hip_fp16.h>

// LiquidLinear: xin = x@Wi^T + bi ; scan: h' = (1-sig(tau))h + sig(tau)tanh(xin_t + h@Wr^T + br)
// outs = hs@Wo^T + bo ; outputs = [outs (B,S,DOUT) fp32][h_final (B,H) fp32]
// B=64 S=1024 DIN=H=DOUT=512
//
// R10: R9 (exchange-free scan: 4 blocks, full Wr fp16 resident per block in
// VGPR+LDS, XOR-swizzled h16 LDS broadcast, fp16 single-pass MFMA) with the
// occupancy declaration FIXED: __launch_bounds__(512, 1).
// R9's (512,2) was treated as 2 blocks/CU -> 4 waves/SIMD -> 128-VGPR cap ->
// the 184 weight VGPRs spilled to L2-backed scratch (VGPR_Count=128 in the
// counters; FETCH_SIZE showed no HBM re-reads because scratch stayed in L2),
// costing ~3us/step. (512,1) -> 1 block/CU -> 2 waves/SIMD -> 256-VGPR cap;
// ~245 needed -> no spill.

typedef _Float16 f16x8 __attribute__((ext_vector_type(8)));
typedef float f32x4 __attribute__((ext_vector_type(4)));
typedef float floatv4 __attribute__((ext_vector_type(4)));
typedef unsigned short ushort4v __attribute__((ext_vector_type(4)));
typedef unsigned int uint4v __attribute__((ext_vector_type(4)));

#define NSTEP 1024

__device__ __forceinline__ unsigned short f2h(float f) {
    _Float16 h = (_Float16)f;
    return *(unsigned short*)&h;
}
__device__ __forceinline__ float tanh_fast(float x) {
    // 1 - 2/(e^{2x}+1): monotone, saturates to +-1 without NaN at extremes
    float e = __expf(2.f * x);
    return 1.f - 2.f / (e + 1.f);
}

// ---------------------------------------------------------------- GEMM1: xin = x @ Wi^T + bi
__global__ __launch_bounds__(256) void gemm_xin(
    const float* __restrict__ X, const float* __restrict__ Wi,
    const float* __restrict__ bi, float* __restrict__ xin)
{
    __shared__ unsigned short As[128][40];
    __shared__ unsigned short Bs[128][40];
    const int bm = blockIdx.x, bn = blockIdx.y;
    const int tid = threadIdx.x, w = tid >> 6, l = tid & 63;
    const int wm = w >> 1, wn = w & 1;
    f32x4 acc[4][4] = {};

    for (int kt = 0; kt < 512; kt += 32) {
        __syncthreads();
        #pragma unroll
        for (int j = 0; j < 4; j++) {
            int q = tid + 256 * j;
            int row = q >> 3, c4 = (q & 7) * 4;
            floatv4 va = *(const floatv4*)&X[(size_t)(bm * 128 + row) * 512 + kt + c4];
            floatv4 vb = *(const floatv4*)&Wi[(size_t)(bn * 128 + row) * 512 + kt + c4];
            ushort4v pa, pb;
            #pragma unroll
            for (int e = 0; e < 4; e++) { pa[e] = f2h(va[e]); pb[e] = f2h(vb[e]); }
            *(ushort4v*)&As[row][c4] = pa;
            *(ushort4v*)&Bs[row][c4] = pb;
        }
        __syncthreads();
        f16x8 a[4], b[4];
        #pragma unroll
        for (int i = 0; i < 4; i++)
            a[i] = *(const f16x8*)&As[wm * 64 + i * 16 + (l & 15)][(l >> 4) * 8];
        #pragma unroll
        for (int i = 0; i < 4; i++)
            b[i] = *(const f16x8*)&Bs[wn * 64 + i * 16 + (l & 15)][(l >> 4) * 8];
        #pragma unroll
        for (int i = 0; i < 4; i++)
            #pragma unroll
            for (int j = 0; j < 4; j++)
                acc[i][j] = __builtin_amdgcn_mfma_f32_16x16x32_f16(a[i], b[j], acc[i][j], 0, 0, 0);
    }
    #pragma unroll
    for (int i = 0; i < 4; i++)
        #pragma unroll
        for (int j = 0; j < 4; j++)
            #pragma unroll
            for (int r = 0; r < 4; r++) {
                int m = bm * 128 + wm * 64 + i * 16 + (l >> 4) * 4 + r;
                int n = bn * 128 + wn * 64 + j * 16 + (l & 15);
                int bb = m >> 10, tt = m & 1023;
                xin[((size_t)tt * 64 + bb) * 512 + n] = acc[i][j][r] + bi[n];
            }
}

// ---------------------------------------------------------------- GEMM3: outs = hs @ Wo^T + bo
__global__ __launch_bounds__(256) void gemm_out(
    const unsigned short* __restrict__ hs, const float* __restrict__ Wo,
    const float* __restrict__ bo, float* __restrict__ out)
{
    __shared__ unsigned short As[128][40];
    __shared__ unsigned short Bs[128][40];
    const int bm = blockIdx.x, bn = blockIdx.y;
    const int tid = threadIdx.x, w = tid >> 6, l = tid & 63;
    const int wm = w >> 1, wn = w & 1;
    f32x4 acc[4][4] = {};

    for (int kt = 0; kt < 512; kt += 32) {
        __syncthreads();
        #pragma unroll
        for (int j = 0; j < 2; j++) {
            int q = tid + 256 * j;
            int row = q >> 2, c8 = (q & 3) * 8;
            int r = bm * 128 + row;
            int ra = (r & 1023) * 64 + (r >> 10);
            f16x8 v = *(const f16x8*)&hs[(size_t)ra * 512 + kt + c8];
            *(f16x8*)&As[row][c8] = v;
        }
        #pragma unroll
        for (int j = 0; j < 4; j++) {
            int q = tid + 256 * j;
            int row = q >> 3, c4 = (q & 7) * 4;
            floatv4 vb = *(const floatv4*)&Wo[(size_t)(bn * 128 + row) * 512 + kt + c4];
            ushort4v pb;
            #pragma unroll
            for (int e = 0; e < 4; e++) pb[e] = f2h(vb[e]);
            *(ushort4v*)&Bs[row][c4] = pb;
        }
        __syncthreads();
        f16x8 a[4], b[4];
        #pragma unroll
        for (int i = 0; i < 4; i++)
            a[i] = *(const f16x8*)&As[wm * 64 + i * 16 + (l & 15)][(l >> 4) * 8];
        #pragma unroll
        for (int i = 0; i < 4; i++)
            b[i] = *(const f16x8*)&Bs[wn * 64 + i * 16 + (l & 15)][(l >> 4) * 8];
        #pragma unroll
        for (int i = 0; i < 4; i++)
            #pragma unroll
            for (int j = 0; j < 4; j++)
                acc[i][j] = __builtin_amdgcn_mfma_f32_16x16x32_f16(a[i], b[j], acc[i][j], 0, 0, 0);
    }
    #pragma unroll
    for (int i = 0; i < 4; i++)
        #pragma unroll
        for (int j = 0; j < 4; j++)
            #pragma unroll
            for (int r = 0; r < 4; r++) {
                int m = bm * 128 + wm * 64 + i * 16 + (l >> 4) * 4 + r;
                int n = bn * 128 + wn * 64 + j * 16 + (l & 15);
                out[(size_t)m * 512 + n] = acc[i][j][r] + bo[n];
            }
}

// ---------------------------------------------------------------- scan (exchange-free)
// 4 blocks; block g owns batches [g*16,+16), computes ALL 512 h-cols per step.
// Wave w owns n-cols [w*64,+64) (4 tiles of 16). Weights per wave: 64KB fp16,
// split VGPR (tiles 0,1: kt<11; tiles 2,3: kt<12 -> 46 frags = 184 regs) and
// LDS (18 chunks x 1KB). h: [16 rows][512] fp16 in LDS, XOR-swizzled
// (byte ^= (row&7)<<4) -> A-frag ds_read_b128 near the bank floor.
// launch_bounds(512,1): 1 block/CU -> 2 waves/SIMD -> 256-VGPR cap (no spill).
__global__ __launch_bounds__(512, 1) void scan_g(
    const float* __restrict__ Wr, const float* __restrict__ brv,
    const float* __restrict__ tau, const float* __restrict__ xin,
    unsigned short* __restrict__ hs, float* __restrict__ hfinal)
{
    const int g = blockIdx.x;
    const int tid = threadIdx.x, w = tid >> 6, l = tid & 63;

    __shared__ unsigned short wlds[73728];   // 144KB: 8 waves x 18 chunks x 512 ushort
    __shared__ unsigned short h16[8192];     // 16KB: h fp16 [16][512], XOR-swizzled

    // zero h16 (h0 = 0)
    ((uint4v*)h16)[tid] = uint4v{0, 0, 0, 0};
    ((uint4v*)h16)[tid + 512] = uint4v{0, 0, 0, 0};

    // ---- load weights: wave w, cols w*64 + tile*16 + (l&15), k = kt*32 + (l>>4)*8
    f16x8 wv0[11], wv1[11], wv2[12], wv3[12];
    #pragma unroll
    for (int kt = 0; kt < 16; kt++) {
        f16x8 f[4];
        #pragma unroll
        for (int tile = 0; tile < 4; tile++) {
            const float* p = &Wr[(size_t)(w * 64 + tile * 16 + (l & 15)) * 512 + kt * 32 + (l >> 4) * 8];
            #pragma unroll
            for (int e = 0; e < 8; e++) f[tile][e] = (_Float16)p[e];
        }
        if (kt < 11) { wv0[kt] = f[0]; wv1[kt] = f[1]; wv2[kt] = f[2]; wv3[kt] = f[3]; }
        else if (kt == 11) {
            wv2[11] = f[2]; wv3[11] = f[3];
            *(f16x8*)&wlds[(w * 18 + 0 + (kt - 11)) * 512 + l * 8] = f[0];
            *(f16x8*)&wlds[(w * 18 + 5 + (kt - 11)) * 512 + l * 8] = f[1];
        } else {
            *(f16x8*)&wlds[(w * 18 + 0  + (kt - 11)) * 512 + l * 8] = f[0];
            *(f16x8*)&wlds[(w * 18 + 5  + (kt - 11)) * 512 + l * 8] = f[1];
            *(f16x8*)&wlds[(w * 18 + 10 + (kt - 12)) * 512 + l * 8] = f[2];
            *(f16x8*)&wlds[(w * 18 + 14 + (kt - 12)) * 512 + l * 8] = f[3];
        }
    }

    // ---- per-col constants (4 tiles)
    float dd[4], dc[4], bb[4];
    #pragma unroll
    for (int tile = 0; tile < 4; tile++) {
        int col = w * 64 + tile * 16 + (l & 15);
        float s = 1.f / (1.f + __expf(-tau[col]));
        dd[tile] = s; dc[tile] = 1.f - s; bb[tile] = brv[col];
    }
    const int mr4 = (l >> 4) * 4;            // this thread's 4 batch rows
    // h state packed fp16 pairs: hpk[tile][rpair] = rows (2rp, 2rp+1)
    unsigned hpk[4][2] = {};

    __syncthreads();                          // h16 zeros + wlds ready

    for (int t = 0; t < NSTEP; ++t) {
        // xin for this step (independent loads; L3-resident; cover under MFMA)
        float xv[4][4];
        #pragma unroll
        for (int tile = 0; tile < 4; tile++)
            #pragma unroll
            for (int r = 0; r < 4; r++)
                xv[tile][r] = xin[((size_t)t * 64 + g * 16 + mr4 + r) * 512
                                  + w * 64 + tile * 16 + (l & 15)];

        // I = h @ Wr^T over all 512 k, 4 acc chains
        f32x4 acc[4] = {};
        #pragma unroll
        for (int kt = 0; kt < 11; kt++) {
            int abyte = (((l & 15) * 1024) + kt * 64 + ((l >> 4) * 16)) ^ ((l & 7) << 4);
            f16x8 ah = *(const f16x8*)((const char*)h16 + abyte);
            acc[0] = __builtin_amdgcn_mfma_f32_16x16x32_f16(ah, wv0[kt], acc[0], 0, 0, 0);
            acc[1] = __builtin_amdgcn_mfma_f32_16x16x32_f16(ah, wv1[kt], acc[1], 0, 0, 0);
            acc[2] = __builtin_amdgcn_mfma_f32_16x16x32_f16(ah, wv2[kt], acc[2], 0, 0, 0);
            acc[3] = __builtin_amdgcn_mfma_f32_16x16x32_f16(ah, wv3[kt], acc[3], 0, 0, 0);
        }
        {   // kt = 11: tiles 0,1 from LDS; tiles 2,3 from VGPR
            int abyte = (((l & 15) * 1024) + 11 * 64 + ((l >> 4) * 16)) ^ ((l & 7) << 4);
            f16x8 ah = *(const f16x8*)((const char*)h16 + abyte);
            f16x8 b0 = *(const f16x8*)&wlds[(w * 18 + 0) * 512 + l * 8];
            f16x8 b1 = *(const f16x8*)&wlds[(w * 18 + 5) * 512 + l * 8];
            acc[0] = __builtin_amdgcn_mfma_f32_16x16x32_f16(ah, b0, acc[0], 0, 0, 0);
            acc[1] = __builtin_amdgcn_mfma_f32_16x16x32_f16(ah, b1, acc[1], 0, 0, 0);
            acc[2] = __builtin_amdgcn_mfma_f32_16x16x32_f16(ah, wv2[11], acc[2], 0, 0, 0);
            acc[3] = __builtin_amdgcn_mfma_f32_16x16x32_f16(ah, wv3[11], acc[3], 0, 0, 0);
        }
        #pragma unroll
        for (int kt = 12; kt < 16; kt++) {
            int abyte = (((l & 15) * 1024) + kt * 64 + ((l >> 4) * 16)) ^ ((l & 7) << 4);
            f16x8 ah = *(const f16x8*)((const char*)h16 + abyte);
            f16x8 b0 = *(const f16x8*)&wlds[(w * 18 + 0  + (kt - 11)) * 512 + l * 8];
            f16x8 b1 = *(const f16x8*)&wlds[(w * 18 + 5  + (kt - 11)) * 512 + l * 8];
            f16x8 b2 = *(const f16x8*)&wlds[(w * 18 + 10 + (kt - 12)) * 512 + l * 8];
            f16x8 b3 = *(const f16x8*)&wlds[(w * 18 + 14 + (kt - 12)) * 512 + l * 8];
            acc[0] = __builtin_amdgcn_mfma_f32_16x16x32_f16(ah, b0, acc[0], 0, 0, 0);
            acc[1] = __builtin_amdgcn_mfma_f32_16x16x32_f16(ah, b1, acc[1], 0, 0, 0);
            acc[2] = __builtin_amdgcn_mfma_f32_16x16x32_f16(ah, b2, acc[2], 0, 0, 0);
            acc[3] = __builtin_amdgcn_mfma_f32_16x16x32_f16(ah, b3, acc[3], 0, 0, 0);
        }
        __syncthreads();                      // all reads of h_t complete

        // update h for this thread's 16 elems (4 tiles x 4 rows)
        #pragma unroll
        for (int tile = 0; tile < 4; tile++) {
            unsigned np[2];
            #pragma unroll
            for (int rp = 0; rp < 2; rp++) {
                unsigned pk = hpk[tile][rp];
                unsigned nv = 0;
                #pragma unroll
                for (int hbit = 0; hbit < 2; hbit++) {
                    int r = rp * 2 + hbit;
                    _Float16 holdh;
                    *(unsigned short*)&holdh = (unsigned short)((pk >> (hbit * 16)) & 0xffff);
                    float I = acc[tile][r] + xv[tile][r] + bb[tile];
                    float hn = dc[tile] * (float)holdh + dd[tile] * tanh_fast(I);
                    unsigned short hq = f2h(hn);
                    nv |= ((unsigned)hq) << (hbit * 16);
                    int row = mr4 + r, col = w * 64 + tile * 16 + (l & 15);
                    int byte = (row * 1024 + col * 2) ^ ((row & 7) << 4);
                    *(unsigned short*)((char*)h16 + byte) = hq;
                    hs[((size_t)t * 64 + g * 16 + row) * 512 + col] = hq;
                }
                np[rp] = nv;
            }
            hpk[tile][0] = np[0]; hpk[tile][1] = np[1];
        }
        __syncthreads();                      // h_{t+1} visible to all waves
    }

    // h_final fp32 (from packed fp16 state)
    #pragma unroll
    for (int tile = 0; tile < 4; tile++)
        #pragma unroll
        for (int r = 0; r < 4; r++) {
            _Float16 hv;
            *(unsigned short*)&hv = (unsigned short)((hpk[tile][r >> 1] >> ((r & 1) * 16)) & 0xffff);
            int col = w * 64 + tile * 16 + (l & 15);
            hfinal[(size_t)(g * 16 + mr4 + r) * 512 + col] = (float)hv;
        }
}

// ---------------------------------------------------------------- launch
extern "C" void kernel_launch(void* const* d_in, const int* in_sizes, int n_in,
                              void* d_out, int out_size, void* d_ws, size_t ws_size,
                              hipStream_t stream) {
    const float* x   = (const float*)d_in[0];
    const float* Wi  = (const float*)d_in[1];
    const float* bi  = (const float*)d_in[2];
    const float* Wr  = (const float*)d_in[3];
    const float* br  = (const float*)d_in[4];
    const float* tau = (const float*)d_in[5];
    const float* Wo  = (const float*)d_in[6];
    const float* bo  = (const float*)d_in[7];

    float* out    = (float*)d_out;
    float* xin    = (float*)d_out;                       // reuse outs region for xin [S,B,H] fp32
    float* hfinal = (float*)d_out + (size_t)33554432;    // after B*S*DOUT

    // ws: hs fp16 [S,B,H] (64 MiB). Nothing else.
    unsigned short* hs = (unsigned short*)d_ws;

    hipLaunchKernelGGL(gemm_xin, dim3(512, 4), dim3(256), 0, stream, x, Wi, bi, xin);
    hipLaunchKernelGGL(scan_g, dim3(4), dim3(512), 0, stream, Wr, br, tau, xin, hs, hfinal);
    hipLaunchKernelGGL(gemm_out, dim3(512, 4), dim3(256), 0, stream, hs, Wo, bo, out);
}